// Round 2
// baseline (2668.300 us; speedup 1.0000x reference)
//
#include <hip/hip_runtime.h>
#include <hip/hip_bf16.h>
#include <math.h>

// Problem constants (from reference)
constexpr int E_EXP = 32;
constexpr int TOPK  = 4;
constexpr int H_DIM = 2048;
constexpr int I_DIM = 2048;
constexpr int T_TOK = 512;
constexpr int CAP   = 256;
constexpr int TWOI  = 4096;           // 2*I
constexpr int NPAIR = T_TOK * TOPK;   // 2048
constexpr float ALPHA = 1.702f;
constexpr float LIMIT = 7.0f;

// NOTE (harness contract): integer inputs arrive as int32 per element.
// gate_up_proj / down_proj are int32 arrays of values in [-127,127].

__device__ __forceinline__ int dot4i8(int a, int b, int c) {
    c += (int)((signed char)(a      )) * (int)((signed char)(b      ));
    c += (int)((signed char)(a >>  8)) * (int)((signed char)(b >>  8));
    c += (int)((signed char)(a >> 16)) * (int)((signed char)(b >> 16));
    c += (int)((signed char)(a >> 24)) * (int)((signed char)(b >> 24));
    return c;
}

__device__ __forceinline__ float waveReduceMax(float v) {
    #pragma unroll
    for (int off = 32; off > 0; off >>= 1)
        v = fmaxf(v, __shfl_xor(v, off, 64));
    return v;
}

// ---------------------------------------------------------------------------
// Router: softmax + top-4 + renormalize. One thread per token.
// ---------------------------------------------------------------------------
__global__ void k_router(const float* __restrict__ logits,
                         int* __restrict__ topk_ids,
                         float* __restrict__ topk_w) {
    int t = blockIdx.x * blockDim.x + threadIdx.x;
    if (t >= T_TOK) return;
    float l[E_EXP];
    float mx = -1e30f;
    #pragma unroll
    for (int e = 0; e < E_EXP; e++) { l[e] = logits[t * E_EXP + e]; mx = fmaxf(mx, l[e]); }
    #pragma unroll
    for (int e = 0; e < E_EXP; e++) { l[e] = expf(l[e] - mx); }

    float v[TOPK]; int id[TOPK];
    #pragma unroll
    for (int k = 0; k < TOPK; k++) {
        float best = -1.0f; int bi = 0;
        #pragma unroll
        for (int e = 0; e < E_EXP; e++) {
            bool taken = false;
            for (int j = 0; j < k; j++) taken = taken || (id[j] == e);
            if (!taken && l[e] > best) { best = l[e]; bi = e; }
        }
        v[k] = best; id[k] = bi;
    }
    float inv = 1.0f / (v[0] + v[1] + v[2] + v[3]);
    #pragma unroll
    for (int k = 0; k < TOPK; k++) {
        topk_ids[t * TOPK + k] = id[k];
        topk_w[t * TOPK + k]   = v[k] * inv;
    }
}

// ---------------------------------------------------------------------------
// Per-token symmetric int8 dynamic quant of hidden_states. One block per token.
// ---------------------------------------------------------------------------
__global__ void k_quant_x(const float* __restrict__ x,
                          signed char* __restrict__ qx,
                          float* __restrict__ xs) {
    int t = blockIdx.x, tid = threadIdx.x;
    const float4* xr = (const float4*)(x + (size_t)t * H_DIM);
    float4 v0 = xr[tid * 2], v1 = xr[tid * 2 + 1];
    float am = fmaxf(fmaxf(fmaxf(fabsf(v0.x), fabsf(v0.y)), fmaxf(fabsf(v0.z), fabsf(v0.w))),
                     fmaxf(fmaxf(fabsf(v1.x), fabsf(v1.y)), fmaxf(fabsf(v1.z), fabsf(v1.w))));
    __shared__ float red[4];
    am = waveReduceMax(am);
    if ((tid & 63) == 0) red[tid >> 6] = am;
    __syncthreads();
    am = fmaxf(fmaxf(red[0], red[1]), fmaxf(red[2], red[3]));
    float s = am * (1.0f / 127.0f);
    if (tid == 0) xs[t] = s;
    float vv[8] = {v0.x, v0.y, v0.z, v0.w, v1.x, v1.y, v1.z, v1.w};
    int out[2]; signed char* ob = (signed char*)out;
    #pragma unroll
    for (int j = 0; j < 8; j++) {
        float q = (s > 0.f) ? rintf(vv[j] / s) : 0.f;   // bit-match round(x/s)
        q = fminf(127.f, fmaxf(-127.f, q));
        ob[j] = (signed char)q;
    }
    ((int2*)(qx + (size_t)t * H_DIM))[tid] = *(int2*)out;
}

// ---------------------------------------------------------------------------
// Dispatch: exact-order per-expert positions via ballot scan. One wave/expert.
// ---------------------------------------------------------------------------
__global__ void k_dispatch(const int* __restrict__ topk_ids,
                           int* __restrict__ pair_pos,
                           int* __restrict__ rows_map,
                           int* __restrict__ counts) {
    int e = blockIdx.x;
    int lane = threadIdx.x;
    int base = 0;
    unsigned long long lt = (1ull << lane) - 1ull;
    if (lane == 63) lt = 0x7FFFFFFFFFFFFFFFull;
    for (int i0 = 0; i0 < NPAIR; i0 += 64) {
        int idx = i0 + lane;
        int ee = topk_ids[idx];
        bool m = (ee == e);
        unsigned long long mask = __ballot(m);
        int pre = __popcll(mask & lt);
        if (m) {
            int pos = base + pre;
            pair_pos[idx] = pos;
            if (pos < CAP) rows_map[e * CAP + pos] = idx;
        }
        base += __popcll(mask);
    }
    if (lane == 0) counts[e] = (base < CAP) ? base : CAP;
}

// Exclusive scan of 32 counts (single thread — trivial).
__global__ void k_scan(const int* __restrict__ counts, int* __restrict__ offs) {
    if (threadIdx.x == 0 && blockIdx.x == 0) {
        int a = 0;
        for (int e = 0; e < E_EXP; e++) { offs[e] = a; a += counts[e]; }
        offs[E_EXP] = a;
    }
}

// ---------------------------------------------------------------------------
// Tiled grouped GEMM core: 64x64 tile, K-chunks of 64. Weights are INT32
// (one weight per int); packed to int8 at LDS-write time.
// ---------------------------------------------------------------------------
#define MT 64
#define NT 64
#define KC 64

// GEMM1: [rows,H] x [H,2I] + dequant + bias + swiglu -> act f32 [rows_compact, I]
__global__ __launch_bounds__(256) void k_gemm1(
    const signed char* __restrict__ qx, const float* __restrict__ xs,
    const int* __restrict__ W, const float* __restrict__ wscale,
    const float* __restrict__ wbias, const int* __restrict__ rows_map,
    const int* __restrict__ counts, const int* __restrict__ offs,
    float* __restrict__ act) {
    int e = blockIdx.z;
    int cnt = counts[e];
    int m0 = blockIdx.y * MT;
    if (m0 >= cnt) return;
    int rb = offs[e];
    int n0 = blockIdx.x * NT;
    int tid = threadIdx.x;
    int tx = tid & 15, ty = tid >> 4;

    __shared__ int a_lds[MT][20];            // [row][k-word], 80B row stride
    __shared__ signed char bT[NT][80];       // [n][k], 80B row stride
    __shared__ int tok_lds[MT];
    __shared__ float s_lds[MT];

    if (tid < MT) {
        int r = m0 + tid;
        int tkn = 0; float sc = 0.f;
        if (r < cnt) { int pair = rows_map[e * CAP + r]; tkn = pair >> 2; sc = xs[tkn]; }
        tok_lds[tid] = tkn; s_lds[tid] = sc;
    }
    __syncthreads();

    int c[4][4];
    #pragma unroll
    for (int m = 0; m < 4; m++)
        #pragma unroll
        for (int n = 0; n < 4; n++) c[m][n] = 0;

    const int* Wb = W + (size_t)e * H_DIM * TWOI;

    for (int k0 = 0; k0 < H_DIM; k0 += KC) {
        #pragma unroll
        for (int j = 0; j < 4; j++) {          // A: 64 rows x 16 words
            int li = tid + 256 * j;
            int r = li >> 4, iw = li & 15;
            int tkn = tok_lds[r];
            a_lds[r][iw] = *(const int*)(qx + (size_t)tkn * H_DIM + k0 + iw * 4);
        }
        #pragma unroll
        for (int j = 0; j < 4; j++) {          // B: 64 k-rows x 64 cols, int32 src
            int li = tid + 256 * j;
            int kk = li >> 4, iw = li & 15;
            int4 wv = *(const int4*)(Wb + (size_t)(k0 + kk) * TWOI + n0 + iw * 4);
            bT[iw * 4 + 0][kk] = (signed char)wv.x;
            bT[iw * 4 + 1][kk] = (signed char)wv.y;
            bT[iw * 4 + 2][kk] = (signed char)wv.z;
            bT[iw * 4 + 3][kk] = (signed char)wv.w;
        }
        __syncthreads();
        #pragma unroll
        for (int kk = 0; kk < 4; kk++) {
            int4 a4[4], b4[4];
            #pragma unroll
            for (int m = 0; m < 4; m++) a4[m] = *(const int4*)&a_lds[ty * 4 + m][kk * 4];
            #pragma unroll
            for (int n = 0; n < 4; n++) b4[n] = *(const int4*)&bT[tx * 4 + n][kk * 16];
            #pragma unroll
            for (int m = 0; m < 4; m++)
                #pragma unroll
                for (int n = 0; n < 4; n++) {
                    c[m][n] = dot4i8(a4[m].x, b4[n].x, c[m][n]);
                    c[m][n] = dot4i8(a4[m].y, b4[n].y, c[m][n]);
                    c[m][n] = dot4i8(a4[m].z, b4[n].z, c[m][n]);
                    c[m][n] = dot4i8(a4[m].w, b4[n].w, c[m][n]);
                }
        }
        __syncthreads();
    }

    // epilogue: dequant + bias + swiglu (interleaved cols), write act f32
    #pragma unroll
    for (int m = 0; m < 4; m++) {
        int r = m0 + ty * 4 + m;
        if (r >= cnt) continue;
        float srow = s_lds[ty * 4 + m];
        float res[2];
        #pragma unroll
        for (int p = 0; p < 2; p++) {
            int c0 = n0 + tx * 4 + 2 * p;
            float g   = (float)c[m][2 * p]     * srow * wscale[e * TWOI + c0]     + wbias[e * TWOI + c0];
            float lin = (float)c[m][2 * p + 1] * srow * wscale[e * TWOI + c0 + 1] + wbias[e * TWOI + c0 + 1];
            g = fminf(g, LIMIT);
            lin = fminf(fmaxf(lin, -LIMIT), LIMIT);
            float sig = 1.0f / (1.0f + expf(-ALPHA * g));
            res[p] = g * sig * (lin + 1.0f);
        }
        *(float2*)(act + ((size_t)(rb + r)) * I_DIM + (n0 >> 1) + tx * 2) =
            make_float2(res[0], res[1]);
    }
}

// Per-row requant of act (compact rows). One block per (e, cap-slot).
__global__ void k_quant_act(const float* __restrict__ act,
                            const int* __restrict__ counts,
                            const int* __restrict__ offs,
                            signed char* __restrict__ aq,
                            float* __restrict__ as_) {
    int e = blockIdx.x / CAP, p = blockIdx.x % CAP;
    if (p >= counts[e]) return;
    int row = offs[e] + p;
    int tid = threadIdx.x;
    const float4* xr = (const float4*)(act + (size_t)row * I_DIM);
    float4 v0 = xr[tid * 2], v1 = xr[tid * 2 + 1];
    float am = fmaxf(fmaxf(fmaxf(fabsf(v0.x), fabsf(v0.y)), fmaxf(fabsf(v0.z), fabsf(v0.w))),
                     fmaxf(fmaxf(fabsf(v1.x), fabsf(v1.y)), fmaxf(fabsf(v1.z), fabsf(v1.w))));
    __shared__ float red[4];
    am = waveReduceMax(am);
    if ((tid & 63) == 0) red[tid >> 6] = am;
    __syncthreads();
    am = fmaxf(fmaxf(red[0], red[1]), fmaxf(red[2], red[3]));
    float s = am * (1.0f / 127.0f);
    if (tid == 0) as_[row] = s;
    float vv[8] = {v0.x, v0.y, v0.z, v0.w, v1.x, v1.y, v1.z, v1.w};
    int out[2]; signed char* ob = (signed char*)out;
    #pragma unroll
    for (int j = 0; j < 8; j++) {
        float q = (s > 0.f) ? rintf(vv[j] / s) : 0.f;
        q = fminf(127.f, fmaxf(-127.f, q));
        ob[j] = (signed char)q;
    }
    ((int2*)(aq + (size_t)row * I_DIM))[tid] = *(int2*)out;
}

// GEMM2: [rows,I] x [I,H] + dequant + bias -> dn_rows f32 [NPAIR, H]
__global__ __launch_bounds__(256) void k_gemm2(
    const signed char* __restrict__ aq, const float* __restrict__ as_,
    const int* __restrict__ W, const float* __restrict__ wscale,
    const float* __restrict__ wbias, const int* __restrict__ rows_map,
    const int* __restrict__ counts, const int* __restrict__ offs,
    float* __restrict__ dn_rows) {
    int e = blockIdx.z;
    int cnt = counts[e];
    int m0 = blockIdx.y * MT;
    if (m0 >= cnt) return;
    int rb = offs[e];
    int n0 = blockIdx.x * NT;
    int tid = threadIdx.x;
    int tx = tid & 15, ty = tid >> 4;

    __shared__ int a_lds[MT][20];
    __shared__ signed char bT[NT][80];
    __shared__ int pair_lds[MT];
    __shared__ float s_lds[MT];

    if (tid < MT) {
        int r = m0 + tid;
        int pr = 0; float sc = 0.f;
        if (r < cnt) { pr = rows_map[e * CAP + r]; sc = as_[rb + r]; }
        pair_lds[tid] = pr; s_lds[tid] = sc;
    }
    __syncthreads();

    int c[4][4];
    #pragma unroll
    for (int m = 0; m < 4; m++)
        #pragma unroll
        for (int n = 0; n < 4; n++) c[m][n] = 0;

    const int* Wb = W + (size_t)e * I_DIM * H_DIM;

    for (int k0 = 0; k0 < I_DIM; k0 += KC) {
        #pragma unroll
        for (int j = 0; j < 4; j++) {
            int li = tid + 256 * j;
            int r = li >> 4, iw = li & 15;
            int rr = rb + m0 + r; if (rr >= NPAIR) rr = NPAIR - 1;   // clamp OOB tail reads
            a_lds[r][iw] = *(const int*)(aq + (size_t)rr * I_DIM + k0 + iw * 4);
        }
        #pragma unroll
        for (int j = 0; j < 4; j++) {
            int li = tid + 256 * j;
            int kk = li >> 4, iw = li & 15;
            int4 wv = *(const int4*)(Wb + (size_t)(k0 + kk) * H_DIM + n0 + iw * 4);
            bT[iw * 4 + 0][kk] = (signed char)wv.x;
            bT[iw * 4 + 1][kk] = (signed char)wv.y;
            bT[iw * 4 + 2][kk] = (signed char)wv.z;
            bT[iw * 4 + 3][kk] = (signed char)wv.w;
        }
        __syncthreads();
        #pragma unroll
        for (int kk = 0; kk < 4; kk++) {
            int4 a4[4], b4[4];
            #pragma unroll
            for (int m = 0; m < 4; m++) a4[m] = *(const int4*)&a_lds[ty * 4 + m][kk * 4];
            #pragma unroll
            for (int n = 0; n < 4; n++) b4[n] = *(const int4*)&bT[tx * 4 + n][kk * 16];
            #pragma unroll
            for (int m = 0; m < 4; m++)
                #pragma unroll
                for (int n = 0; n < 4; n++) {
                    c[m][n] = dot4i8(a4[m].x, b4[n].x, c[m][n]);
                    c[m][n] = dot4i8(a4[m].y, b4[n].y, c[m][n]);
                    c[m][n] = dot4i8(a4[m].z, b4[n].z, c[m][n]);
                    c[m][n] = dot4i8(a4[m].w, b4[n].w, c[m][n]);
                }
        }
        __syncthreads();
    }

    #pragma unroll
    for (int m = 0; m < 4; m++) {
        int r = m0 + ty * 4 + m;
        if (r >= cnt) continue;
        float srow = s_lds[ty * 4 + m];
        int pair = pair_lds[ty * 4 + m];
        #pragma unroll
        for (int n = 0; n < 4; n++) {
            int col = n0 + tx * 4 + n;
            float val = (float)c[m][n] * srow * wscale[e * H_DIM + col] + wbias[e * H_DIM + col];
            dn_rows[(size_t)pair * H_DIM + col] = val;
        }
    }
}

// Finalize: out[t] = sum_k w[t,k] * dn_rows[t*K+k] (valid only). Block per token.
__global__ void k_finalize(const float* __restrict__ dn_rows,
                           const float* __restrict__ topk_w,
                           const int* __restrict__ pair_pos,
                           float* __restrict__ out) {
    int t = blockIdx.x, tid = threadIdx.x;
    int h = tid * 8;
    float acc[8] = {0, 0, 0, 0, 0, 0, 0, 0};
    #pragma unroll
    for (int k = 0; k < TOPK; k++) {
        int pair = t * TOPK + k;
        if (pair_pos[pair] < CAP) {
            float w = topk_w[pair];
            const float4* dr = (const float4*)(dn_rows + (size_t)pair * H_DIM + h);
            float4 d0 = dr[0], d1 = dr[1];
            acc[0] += w * d0.x; acc[1] += w * d0.y; acc[2] += w * d0.z; acc[3] += w * d0.w;
            acc[4] += w * d1.x; acc[5] += w * d1.y; acc[6] += w * d1.z; acc[7] += w * d1.w;
        }
    }
    float4* o = (float4*)(out + (size_t)t * H_DIM + h);
    o[0] = make_float4(acc[0], acc[1], acc[2], acc[3]);
    o[1] = make_float4(acc[4], acc[5], acc[6], acc[7]);
}

// ---------------------------------------------------------------------------
extern "C" void kernel_launch(void* const* d_in, const int* in_sizes, int n_in,
                              void* d_out, int out_size, void* d_ws, size_t ws_size,
                              hipStream_t stream) {
    const float* hidden  = (const float*)d_in[0];
    const float* rlogits = (const float*)d_in[1];
    const int*   gup     = (const int*)d_in[2];    // int8 values stored as int32
    const float* gup_s   = (const float*)d_in[3];
    const float* gup_b   = (const float*)d_in[4];
    const int*   dnw     = (const int*)d_in[5];    // int8 values stored as int32
    const float* dn_s    = (const float*)d_in[6];
    const float* dn_b    = (const float*)d_in[7];
    float*       out     = (float*)d_out;

    char* ws = (char*)d_ws;
    size_t off = 0;
    auto alloc = [&](size_t bytes) -> void* {
        void* p = ws + off;
        off = (off + bytes + 255) & ~(size_t)255;
        return p;
    };
    signed char* qx       = (signed char*)alloc((size_t)T_TOK * H_DIM);          // 1 MB
    float*       xs       = (float*)alloc((size_t)T_TOK * 4);
    int*         topk_ids = (int*)alloc((size_t)NPAIR * 4);
    float*       topk_w   = (float*)alloc((size_t)NPAIR * 4);
    int*         pair_pos = (int*)alloc((size_t)NPAIR * 4);
    int*         rows_map = (int*)alloc((size_t)E_EXP * CAP * 4);
    int*         counts   = (int*)alloc((size_t)E_EXP * 4);
    int*         offs     = (int*)alloc((size_t)(E_EXP + 1) * 4);
    float*       act      = (float*)alloc((size_t)NPAIR * I_DIM * 4);            // 16 MB
    signed char* aq       = (signed char*)alloc((size_t)NPAIR * I_DIM);          // 4 MB
    float*       as_      = (float*)alloc((size_t)NPAIR * 4);
    float*       dnr      = (float*)alloc((size_t)NPAIR * H_DIM * 4);            // 16 MB

    k_router<<<dim3((T_TOK + 255) / 256), dim3(256), 0, stream>>>(rlogits, topk_ids, topk_w);
    k_quant_x<<<dim3(T_TOK), dim3(256), 0, stream>>>(hidden, qx, xs);
    k_dispatch<<<dim3(E_EXP), dim3(64), 0, stream>>>(topk_ids, pair_pos, rows_map, counts);
    k_scan<<<dim3(1), dim3(64), 0, stream>>>(counts, offs);
    k_gemm1<<<dim3(TWOI / NT, CAP / MT, E_EXP), dim3(256), 0, stream>>>(
        qx, xs, gup, gup_s, gup_b, rows_map, counts, offs, act);
    k_quant_act<<<dim3(E_EXP * CAP), dim3(256), 0, stream>>>(act, counts, offs, aq, as_);
    k_gemm2<<<dim3(H_DIM / NT, CAP / MT, E_EXP), dim3(256), 0, stream>>>(
        aq, as_, dnw, dn_s, dn_b, rows_map, counts, offs, dnr);
    k_finalize<<<dim3(T_TOK), dim3(256), 0, stream>>>(dnr, topk_w, pair_pos, out);
}